// Round 17
// baseline (170.037 us; speedup 1.0000x reference)
//
#include <hip/hip_runtime.h>
#include <stdint.h>

#define CIN   256
#define COUT  128
#define HH    128
#define WW    128
#define NIMG  16

typedef unsigned long long u64;
typedef unsigned int u32;
typedef unsigned short u16;
typedef u32 u32x4 __attribute__((ext_vector_type(4)));
typedef int i32x4 __attribute__((ext_vector_type(4)));
typedef int i32x16 __attribute__((ext_vector_type(16)));
typedef signed char i8;

// ---------------------------------------------------------------------------
// Pack sign bits of x: px[(n*HH+h)*WW + w][word 0..3]; bit (c&63) of word
// (c>>6) = (x[n][c][h][w] > 0). 32 B per position. ~45 us (HBM roofline).
// ---------------------------------------------------------------------------
__global__ __launch_bounds__(256) void pack_x_kernel(const float* __restrict__ x,
                                                     u64* __restrict__ px) {
    int t = blockIdx.x * 256 + threadIdx.x;
    int w = t & (WW - 1);
    int h = (t >> 7) & (HH - 1);
    int n = t >> 14;
    const float* xp = x + (size_t)n * CIN * HH * WW + (size_t)h * WW + w;
    u64 words[4];
#pragma unroll
    for (int wd = 0; wd < 4; ++wd) {
        u64 acc = 0;
#pragma unroll 16
        for (int cc = 0; cc < 64; ++cc) {
            float v = xp[(size_t)(wd * 64 + cc) * (HH * WW)];
            acc |= (u64)(v > 0.0f) << cc;
        }
        words[wd] = acc;
    }
    ulonglong2* o = reinterpret_cast<ulonglong2*>(px + (size_t)t * 4);
    o[0] = make_ulonglong2(words[0], words[1]);
    o[1] = make_ulonglong2(words[2], words[3]);
}

// ---------------------------------------------------------------------------
// W -> k16-group-major i8 table wg[k16][co][16]; wsum[pat][co] = sum of
// valid-tap weights per border pattern; alpha[co] = mean|W|. (v13-proven)
// ---------------------------------------------------------------------------
__global__ __launch_bounds__(256) void pack_w_kernel(const float* __restrict__ wt,
                                                     i8* __restrict__ wg,
                                                     short* __restrict__ wsum,
                                                     float* __restrict__ alpha) {
    int co = blockIdx.x;
    int c  = threadIdx.x;            // input channel
    int lane = c & 63;
    int word = c >> 6;
    __shared__ u64 wsh[9][4];
    __shared__ int pct[9];
    __shared__ float red[4];
    const float* wp = wt + ((size_t)co * CIN + c) * 9;
    float asum = 0.0f;
#pragma unroll
    for (int k = 0; k < 9; ++k) {
        float v = wp[k];
        asum += fabsf(v);
        u64 m = __ballot(v > 0.0f);
        if (lane == 0) wsh[k][word] = m;
        int k16g = k * 16 + (c >> 4);
        wg[((size_t)k16g * COUT + co) * 16 + (c & 15)] = (v > 0.0f) ? (i8)1 : (i8)-1;
    }
    for (int off = 32; off > 0; off >>= 1) asum += __shfl_down(asum, off);
    if (lane == 0) red[word] = asum;
    __syncthreads();
    if (c < 9)
        pct[c] = __popcll(wsh[c][0]) + __popcll(wsh[c][1]) +
                 __popcll(wsh[c][2]) + __popcll(wsh[c][3]);
    if (c == 0) alpha[co] = (red[0] + red[1] + red[2] + red[3]) * (1.0f / 2304.0f);
    __syncthreads();
    if (c < 9) {
        int pat = c, ht = pat / 3, wtp = pat % 3;
        int s = 0;
#pragma unroll
        for (int k = 0; k < 9; ++k) {
            int dh = k / 3 - 1, dw = k % 3 - 1;
            bool inv = (dh == -1 && ht == 0) || (dh == 1 && ht == 2) ||
                       (dw == -1 && wtp == 0) || (dw == 1 && wtp == 2);
            if (!inv) s += 2 * pct[k] - 256;   // sum of +-1 weights, valid taps
        }
        wsum[pat * COUT + co] = (short)s;
    }
}

// 16 k-bits -> 16 i8 bytes of {0,1}. __umul24: full-rate (v_mul_lo_u32 is
// quarter-rate -- R16's hidden VALU cost). Operands < 2^24 by construction.
__device__ __forceinline__ i32x4 spread16(u32 v) {
    u32 o0 = __umul24((v      ) & 15u, 0x00204081u) & 0x01010101u;
    u32 o1 = __umul24((v >>  4) & 15u, 0x00204081u) & 0x01010101u;
    u32 o2 = __umul24((v >>  8) & 15u, 0x00204081u) & 0x01010101u;
    u32 o3 = __umul24((v >> 12) & 15u, 0x00204081u) & 0x01010101u;
    i32x4 r = {(int)o0, (int)o1, (int)o2, (int)o3};
    return r;
}

// ---------------------------------------------------------------------------
// XNOR conv v14 -- 32pos x 128co wave tile. R16 forensics: conv ~100us,
// still VALU-bound: per chunk/wave MFMA 146cyc < VALU ~200+ (spread16's
// v_mul_lo_u32 is QUARTER-rate; X expanded twice -- both co-group waves
// redo the same pos fragments). Fix: wave owns pos0=wave*32, ALL 128 co ->
// per k-step 1 ds_read_u16 + 1 spread16 (umul24) + 4 coalesced W loads
// (L1-resident, shared by all waves) + 4 MFMA. VALU/chunk ~100cyc < MFMA
// 146cyc -> MFMA-bound. {0,1} algebra + wsum border table + zero main-loop
// barriers carried from v13 (absmax 0 proven).
// out[n][co][h][w] = (float)(2*S - wsum) * alpha[w]   (alpha by WIDTH!)
// ---------------------------------------------------------------------------
__global__ __launch_bounds__(256, 4) void conv_kernel(const u64* __restrict__ px,
                                                      const i8* __restrict__ wg,
                                                      const short* __restrict__ wsum,
                                                      const float* __restrict__ alpha,
                                                      float* __restrict__ out) {
    __shared__ u16 xlt[3][16][130];                  // 12480 B, packed bits
    __shared__ short wsl[9 * COUT];                  // 2304 B
    __shared__ float alds[WW];                       // 512 B

    int tid = threadIdx.x;
    int bid = blockIdx.x;                 // n*128 + h
    int h = bid & (HH - 1);
    int n = bid >> 7;

    if (tid < WW) alds[tid] = alpha[tid];
    {
        const u32* s = reinterpret_cast<const u32*>(wsum);
        u32* d = reinterpret_cast<u32*>(wsl);
        for (int i = tid; i < 9 * COUT / 2; i += 256) d[i] = s[i];
    }

    // ---- X stage: packed bits -> transposed u16 planes (halo = 0 bits ->
    //      spread16 gives xb=0 == correct zero padding) ----
    for (int t = tid; t < 390; t += 256) {
        int r = (t >= 260) ? 2 : ((t >= 130) ? 1 : 0);
        int p = t - r * 130;              // col 0..129; position w = p-1
        int gh = h - 1 + r;
        u32 bw[8] = {0, 0, 0, 0, 0, 0, 0, 0};
        if ((p >= 1) && (p <= 128) && (gh >= 0) && (gh < HH)) {
            const u32x4* s = reinterpret_cast<const u32x4*>(
                px + (size_t)((n * HH + gh) * WW + (p - 1)) * 4);
            u32x4 a = s[0], b = s[1];
            bw[0] = a.x; bw[1] = a.y; bw[2] = a.z; bw[3] = a.w;
            bw[4] = b.x; bw[5] = b.y; bw[6] = b.z; bw[7] = b.w;
        }
#pragma unroll
        for (int k16 = 0; k16 < 16; ++k16)
            xlt[r][k16][p] = (u16)(bw[k16 >> 1] >> ((k16 & 1) * 16));
    }
    __syncthreads();                      // the ONLY barrier

    // ---- main K loop: 18 chunks x 4 k-steps, no barriers ----
    int lane = tid & 63;
    int wave = tid >> 6;                  // 0..3
    int l31 = lane & 31;
    int hi  = lane >> 5;
    int pos0 = wave * 32;                 // 32 positions per wave, all 128 co

    i32x16 acc0 = {}, acc1 = {}, acc2 = {}, acc3 = {};   // co 0/32/64/96

#pragma unroll 1
    for (int ch = 0; ch < 18; ++ch) {
        int tap = ch >> 1;
        int k16b = (ch & 1) * 8;          // tap-local u16-plane base
        int r   = tap / 3;
        int dwi = tap - r * 3;            // col = pos + dwi (halo absorbs -1)
        int col = pos0 + l31 + dwi;
#pragma unroll
        for (int ks = 0; ks < 4; ++ks) {
            int k16 = k16b + ks * 2 + hi;
            i32x4 xf = spread16((u32)xlt[r][k16][col]);     // {0,1} bytes
            int k16g = tap * 16 + k16;
            const i32x4* wp = reinterpret_cast<const i32x4*>(
                wg + ((size_t)k16g * COUT) * 16);
            i32x4 wf0 = wp[l31];               // coalesced 512B per 32 lanes
            i32x4 wf1 = wp[32 + l31];
            i32x4 wf2 = wp[64 + l31];
            i32x4 wf3 = wp[96 + l31];
            acc0 = __builtin_amdgcn_mfma_i32_32x32x32_i8(wf0, xf, acc0, 0, 0, 0);
            acc1 = __builtin_amdgcn_mfma_i32_32x32x32_i8(wf1, xf, acc1, 0, 0, 0);
            acc2 = __builtin_amdgcn_mfma_i32_32x32x32_i8(wf2, xf, acc2, 0, 0, 0);
            acc3 = __builtin_amdgcn_mfma_i32_32x32x32_i8(wf3, xf, acc3, 0, 0, 0);
        }
    }

    // ---- epilogue: out = (2*S - wsum[pat][co]) * alpha[w] ----
    int hpat = (h == 0) ? 0 : ((h == HH - 1) ? 2 : 1);
    int wcol = pos0 + l31;
    float aw = alds[wcol];                // faithful broadcast: alpha[WIDTH]
    int wpat = (wcol == 0) ? 0 : ((wcol == WW - 1) ? 2 : 1);
    const short* wsp = &wsl[(hpat * 3 + wpat) * COUT];
    float* ob = out + ((size_t)n * COUT * HH + h) * WW + wcol;
#pragma unroll
    for (int reg = 0; reg < 16; ++reg) {
        int rr = (reg & 3) + 8 * (reg >> 2) + 4 * hi;
        ob[(size_t)(rr)       * (HH * WW)] = (float)(2 * acc0[reg] - (int)wsp[rr])       * aw;
        ob[(size_t)(rr + 32)  * (HH * WW)] = (float)(2 * acc1[reg] - (int)wsp[rr + 32])  * aw;
        ob[(size_t)(rr + 64)  * (HH * WW)] = (float)(2 * acc2[reg] - (int)wsp[rr + 64])  * aw;
        ob[(size_t)(rr + 96)  * (HH * WW)] = (float)(2 * acc3[reg] - (int)wsp[rr + 96])  * aw;
    }
}

extern "C" void kernel_launch(void* const* d_in, const int* in_sizes, int n_in,
                              void* d_out, int out_size, void* d_ws, size_t ws_size,
                              hipStream_t stream) {
    const float* x  = (const float*)d_in[0];
    const float* wt = (const float*)d_in[1];
    float* out = (float*)d_out;

    char* ws = (char*)d_ws;
    const size_t PX_BYTES = (size_t)NIMG * HH * WW * 4 * sizeof(u64);  // 8 MiB
    const size_t WG_BYTES = (size_t)144 * COUT * 16;                   // 288 KiB
    const size_t WS_BYTES = (size_t)9 * COUT * sizeof(short);          // 2.25 KiB
    const size_t AL_BYTES = 512;
    if (ws_size < PX_BYTES + WG_BYTES + WS_BYTES + AL_BYTES) return;
    u64*   px    = (u64*)ws;
    i8*    wg    = (i8*)(ws + PX_BYTES);
    short* wsum  = (short*)(ws + PX_BYTES + WG_BYTES);
    float* alpha = (float*)(ws + PX_BYTES + WG_BYTES + WS_BYTES);

    pack_x_kernel<<<NIMG * HH * WW / 256, 256, 0, stream>>>(x, px);
    pack_w_kernel<<<COUT, 256, 0, stream>>>(wt, wg, wsum, alpha);
    conv_kernel<<<NIMG * HH, 256, 0, stream>>>(px, wg, wsum, alpha, out);
}

// Round 18
// 146.914 us; speedup vs baseline: 1.1574x; 1.1574x over previous
//
#include <hip/hip_runtime.h>
#include <stdint.h>

#define CIN   256
#define COUT  128
#define HH    128
#define WW    128
#define NIMG  16

typedef unsigned long long u64;
typedef unsigned int u32;
typedef unsigned short u16;
typedef u32 u32x4 __attribute__((ext_vector_type(4)));
typedef int i32x4 __attribute__((ext_vector_type(4)));
typedef int i32x16 __attribute__((ext_vector_type(16)));
typedef signed char i8;

// ---------------------------------------------------------------------------
// Pack sign bits of x: px[(n*HH+h)*WW + w][word 0..3]; bit (c&63) of word
// (c>>6) = (x[n][c][h][w] > 0). 32 B per position. ~45 us (HBM roofline).
// ---------------------------------------------------------------------------
__global__ __launch_bounds__(256) void pack_x_kernel(const float* __restrict__ x,
                                                     u64* __restrict__ px) {
    int t = blockIdx.x * 256 + threadIdx.x;
    int w = t & (WW - 1);
    int h = (t >> 7) & (HH - 1);
    int n = t >> 14;
    const float* xp = x + (size_t)n * CIN * HH * WW + (size_t)h * WW + w;
    u64 words[4];
#pragma unroll
    for (int wd = 0; wd < 4; ++wd) {
        u64 acc = 0;
#pragma unroll 16
        for (int cc = 0; cc < 64; ++cc) {
            float v = xp[(size_t)(wd * 64 + cc) * (HH * WW)];
            acc |= (u64)(v > 0.0f) << cc;
        }
        words[wd] = acc;
    }
    ulonglong2* o = reinterpret_cast<ulonglong2*>(px + (size_t)t * 4);
    o[0] = make_ulonglong2(words[0], words[1]);
    o[1] = make_ulonglong2(words[2], words[3]);
}

// ---------------------------------------------------------------------------
// W -> k16-group-major i8 table wg[k16][co][16]; wsum[pat][co] = sum of
// valid-tap weights per border pattern; alpha[co] = mean|W|. (v13-proven)
// ---------------------------------------------------------------------------
__global__ __launch_bounds__(256) void pack_w_kernel(const float* __restrict__ wt,
                                                     i8* __restrict__ wg,
                                                     short* __restrict__ wsum,
                                                     float* __restrict__ alpha) {
    int co = blockIdx.x;
    int c  = threadIdx.x;            // input channel
    int lane = c & 63;
    int word = c >> 6;
    __shared__ u64 wsh[9][4];
    __shared__ int pct[9];
    __shared__ float red[4];
    const float* wp = wt + ((size_t)co * CIN + c) * 9;
    float asum = 0.0f;
#pragma unroll
    for (int k = 0; k < 9; ++k) {
        float v = wp[k];
        asum += fabsf(v);
        u64 m = __ballot(v > 0.0f);
        if (lane == 0) wsh[k][word] = m;
        int k16g = k * 16 + (c >> 4);
        wg[((size_t)k16g * COUT + co) * 16 + (c & 15)] = (v > 0.0f) ? (i8)1 : (i8)-1;
    }
    for (int off = 32; off > 0; off >>= 1) asum += __shfl_down(asum, off);
    if (lane == 0) red[word] = asum;
    __syncthreads();
    if (c < 9)
        pct[c] = __popcll(wsh[c][0]) + __popcll(wsh[c][1]) +
                 __popcll(wsh[c][2]) + __popcll(wsh[c][3]);
    if (c == 0) alpha[co] = (red[0] + red[1] + red[2] + red[3]) * (1.0f / 2304.0f);
    __syncthreads();
    if (c < 9) {
        int pat = c, ht = pat / 3, wtp = pat % 3;
        int s = 0;
#pragma unroll
        for (int k = 0; k < 9; ++k) {
            int dh = k / 3 - 1, dw = k % 3 - 1;
            bool inv = (dh == -1 && ht == 0) || (dh == 1 && ht == 2) ||
                       (dw == -1 && wtp == 0) || (dw == 1 && wtp == 2);
            if (!inv) s += 2 * pct[k] - 256;   // sum of +-1 weights, valid taps
        }
        wsum[pat * COUT + co] = (short)s;
    }
}

// 16 k-bits -> 16 i8 bytes of {0,1}. __umul24 = v_mul_u32_u24 (FULL rate;
// v_mul_lo_u32 is quarter-rate -- R16/R17's hidden VALU cost).
__device__ __forceinline__ i32x4 spread16(u32 v) {
    u32 o0 = __umul24((v      ) & 15u, 0x00204081u) & 0x01010101u;
    u32 o1 = __umul24((v >>  4) & 15u, 0x00204081u) & 0x01010101u;
    u32 o2 = __umul24((v >>  8) & 15u, 0x00204081u) & 0x01010101u;
    u32 o3 = __umul24((v >> 12) & 15u, 0x00204081u) & 0x01010101u;
    i32x4 r = {(int)o0, (int)o1, (int)o2, (int)o3};
    return r;
}

// ---------------------------------------------------------------------------
// XNOR conv v15 -- v13 tile (64pos x 64co, the balanced 2x2; v14's 1x4 tile
// doubled W traffic and REGRESSED 150->170) + two cuts:
// (1) umul24 spread: VALU/chunk 480 -> ~270 cyc (total VALU 29 -> ~15us,
//     now under the 35us MFMA pipe).
// (2) ping-pong W prefetch in registers (wA/wB, statically indexed): chunk
//     ch+1's 8 coalesced dwordx4 issue before chunk ch's MFMAs -> ~586cyc
//     deterministic latency cover (v13 had zero prefetch distance).
// Cost: ~150 VGPR -> launch_bounds(256,3), 12 waves/CU. {0,1} algebra +
// wsum border table + zero main-loop barriers carried from v13 (absmax 0).
// out[n][co][h][w] = (float)(2*S - wsum) * alpha[w]   (alpha by WIDTH!)
// ---------------------------------------------------------------------------
#define COMPUTE_CHUNK(CH, WREG)                                               \
    {                                                                         \
        int tap  = (CH) >> 1;                                                 \
        int k16b = ((CH) & 1) * 8;                                            \
        int r    = tap / 3;                                                   \
        int dwi  = tap - r * 3;                                               \
        int colA = pos0 + l31 + dwi;                                          \
        int colB = colA + 32;                                                 \
        _Pragma("unroll")                                                     \
        for (int ks = 0; ks < 4; ++ks) {                                      \
            int k16 = k16b + ks * 2 + hi;                                     \
            i32x4 xfA = spread16((u32)xlt[r][k16][colA]);                     \
            i32x4 xfB = spread16((u32)xlt[r][k16][colB]);                     \
            accA0 = __builtin_amdgcn_mfma_i32_32x32x32_i8(WREG[2*ks],   xfA, accA0, 0, 0, 0); \
            accA1 = __builtin_amdgcn_mfma_i32_32x32x32_i8(WREG[2*ks+1], xfA, accA1, 0, 0, 0); \
            accB0 = __builtin_amdgcn_mfma_i32_32x32x32_i8(WREG[2*ks],   xfB, accB0, 0, 0, 0); \
            accB1 = __builtin_amdgcn_mfma_i32_32x32x32_i8(WREG[2*ks+1], xfB, accB1, 0, 0, 0); \
        }                                                                     \
    }

__global__ __launch_bounds__(256, 3) void conv_kernel(const u64* __restrict__ px,
                                                      const i8* __restrict__ wg,
                                                      const short* __restrict__ wsum,
                                                      const float* __restrict__ alpha,
                                                      float* __restrict__ out) {
    __shared__ u16 xlt[3][16][130];                  // 12480 B, packed bits
    __shared__ short wsl[9 * COUT];                  // 2304 B
    __shared__ float alds[WW];                       // 512 B

    int tid = threadIdx.x;
    int bid = blockIdx.x;                 // n*128 + h
    int h = bid & (HH - 1);
    int n = bid >> 7;

    if (tid < WW) alds[tid] = alpha[tid];
    {
        const u32* s = reinterpret_cast<const u32*>(wsum);
        u32* d = reinterpret_cast<u32*>(wsl);
        for (int i = tid; i < 9 * COUT / 2; i += 256) d[i] = s[i];
    }

    // ---- X stage: packed bits -> transposed u16 planes (halo = 0 bits ->
    //      spread16 gives xb=0 == correct zero padding) ----
    for (int t = tid; t < 390; t += 256) {
        int r = (t >= 260) ? 2 : ((t >= 130) ? 1 : 0);
        int p = t - r * 130;              // col 0..129; position w = p-1
        int gh = h - 1 + r;
        u32 bw[8] = {0, 0, 0, 0, 0, 0, 0, 0};
        if ((p >= 1) && (p <= 128) && (gh >= 0) && (gh < HH)) {
            const u32x4* s = reinterpret_cast<const u32x4*>(
                px + (size_t)((n * HH + gh) * WW + (p - 1)) * 4);
            u32x4 a = s[0], b = s[1];
            bw[0] = a.x; bw[1] = a.y; bw[2] = a.z; bw[3] = a.w;
            bw[4] = b.x; bw[5] = b.y; bw[6] = b.z; bw[7] = b.w;
        }
#pragma unroll
        for (int k16 = 0; k16 < 16; ++k16)
            xlt[r][k16][p] = (u16)(bw[k16 >> 1] >> ((k16 & 1) * 16));
    }
    __syncthreads();                      // the ONLY barrier

    int lane = tid & 63;
    int wave = tid >> 6;                  // 0..3
    int l31 = lane & 31;
    int hi  = lane >> 5;
    int co0  = (wave & 1) * 64;           // co groups: co0, co0+32
    int pos0 = (wave >> 1) * 64;          // pos groups: pos0, pos0+32

    i32x16 accA0 = {}, accA1 = {}, accB0 = {}, accB1 = {};  // [pos][co]

    // W fragment base: + k16g*2048 + sel*512  (k16g = tap*16 + k16b + ks*2 + hi)
    const i8* wgb = wg + ((size_t)co0 + l31) * 16;
#define WFRAG(CH, KS, SEL)                                                    \
    (*reinterpret_cast<const i32x4*>(wgb +                                    \
        (size_t)(((CH) >> 1) * 16 + ((CH) & 1) * 8 + (KS) * 2 + hi) * 2048 +  \
        (SEL) * 512))

    i32x4 wA[8], wB[8];
#pragma unroll
    for (int ks = 0; ks < 4; ++ks) {      // preload chunk 0
        wA[2 * ks]     = WFRAG(0, ks, 0);
        wA[2 * ks + 1] = WFRAG(0, ks, 1);
    }

#pragma unroll 1
    for (int ch2 = 0; ch2 < 9; ++ch2) {
        int chA = 2 * ch2, chB = 2 * ch2 + 1;
#pragma unroll
        for (int ks = 0; ks < 4; ++ks) {  // issue chB loads before chA compute
            wB[2 * ks]     = WFRAG(chB, ks, 0);
            wB[2 * ks + 1] = WFRAG(chB, ks, 1);
        }
        COMPUTE_CHUNK(chA, wA);
        if (ch2 < 8) {
#pragma unroll
            for (int ks = 0; ks < 4; ++ks) {  // issue next chA loads
                wA[2 * ks]     = WFRAG(chA + 2, ks, 0);
                wA[2 * ks + 1] = WFRAG(chA + 2, ks, 1);
            }
        }
        COMPUTE_CHUNK(chB, wB);
    }
#undef WFRAG

    // ---- epilogue: out = (2*S - wsum[pat][co]) * alpha[w] ----
    int hpat = (h == 0) ? 0 : ((h == HH - 1) ? 2 : 1);
#pragma unroll
    for (int half = 0; half < 2; ++half) {
        int wcol = pos0 + half * 32 + l31;
        float aw = alds[wcol];            // faithful broadcast: alpha[WIDTH]
        int wpat = (wcol == 0) ? 0 : ((wcol == WW - 1) ? 2 : 1);
        const short* wsp = &wsl[(hpat * 3 + wpat) * COUT];
        i32x16 a0 = half ? accB0 : accA0;
        i32x16 a1 = half ? accB1 : accA1;
#pragma unroll
        for (int reg = 0; reg < 16; ++reg) {
            int rr = (reg & 3) + 8 * (reg >> 2) + 4 * hi;
            int coa = co0 + rr;
            int cob = co0 + 32 + rr;
            out[((size_t)(n * COUT + coa) * HH + h) * WW + wcol] =
                (float)(2 * a0[reg] - (int)wsp[coa]) * aw;
            out[((size_t)(n * COUT + cob) * HH + h) * WW + wcol] =
                (float)(2 * a1[reg] - (int)wsp[cob]) * aw;
        }
    }
}

extern "C" void kernel_launch(void* const* d_in, const int* in_sizes, int n_in,
                              void* d_out, int out_size, void* d_ws, size_t ws_size,
                              hipStream_t stream) {
    const float* x  = (const float*)d_in[0];
    const float* wt = (const float*)d_in[1];
    float* out = (float*)d_out;

    char* ws = (char*)d_ws;
    const size_t PX_BYTES = (size_t)NIMG * HH * WW * 4 * sizeof(u64);  // 8 MiB
    const size_t WG_BYTES = (size_t)144 * COUT * 16;                   // 288 KiB
    const size_t WS_BYTES = (size_t)9 * COUT * sizeof(short);          // 2.25 KiB
    const size_t AL_BYTES = 512;
    if (ws_size < PX_BYTES + WG_BYTES + WS_BYTES + AL_BYTES) return;
    u64*   px    = (u64*)ws;
    i8*    wg    = (i8*)(ws + PX_BYTES);
    short* wsum  = (short*)(ws + PX_BYTES + WG_BYTES);
    float* alpha = (float*)(ws + PX_BYTES + WG_BYTES + WS_BYTES);

    pack_x_kernel<<<NIMG * HH * WW / 256, 256, 0, stream>>>(x, px);
    pack_w_kernel<<<COUT, 256, 0, stream>>>(wt, wg, wsum, alpha);
    conv_kernel<<<NIMG * HH, 256, 0, stream>>>(px, wg, wsum, alpha, out);
}